// Round 11
// baseline (1397.316 us; speedup 1.0000x reference)
//
#include <hip/hip_runtime.h>
#include <hip/hip_bf16.h>

// LSTM B=256,T=512,I=64,H=256. 64 WGs x 1024 thr, 4-way j-split.
// Round 11 (r10 fixed): wave-local cell via ds_swizzle transpose (no B1/gl),
// act double-buffered (1 barrier/step), 3-deep pipelined poll, counted vmcnt.

#define B_TOT 256
#define T_SEQ 512
#define NIN   64
#define HID   256
#define CHUNK 16
#define JSL   64            // j per WG (4-way split)
#define ROWB  768           // LDS act row stride bytes (320 f16 = 640B data)
#define NKK   10            // K = 320 = 10*32
#define NWG   64

typedef _Float16 half8 __attribute__((ext_vector_type(8)));
typedef float    f32x4 __attribute__((ext_vector_type(4)));
typedef unsigned u32x4 __attribute__((ext_vector_type(4)));

__device__ __forceinline__ float fast_rcp(float x){ return __builtin_amdgcn_rcpf(x); }
__device__ __forceinline__ float sigf(float v){ return fast_rcp(1.0f+__expf(-v)); }
__device__ __forceinline__ float tanhf_fast(float v){ return 1.0f-2.0f*fast_rcp(__expf(2.0f*v)+1.0f); }
__device__ __forceinline__ unsigned short f2h_bits(float f){
    _Float16 h=(_Float16)f; return __builtin_bit_cast(unsigned short,h);
}
template<int IMM>
__device__ __forceinline__ float swz(float v){
    return __builtin_bit_cast(float,
        __builtin_amdgcn_ds_swizzle(__builtin_bit_cast(int, v), IMM));
}

#define PISSUE(V) asm volatile("global_load_dwordx4 %0, %1, off sc0 sc1" \
                               : "=v"(V) : "v"(ap) : "memory")
#define PWAIT()   do { asm volatile("s_waitcnt vmcnt(2)" ::: "memory"); \
                       __builtin_amdgcn_sched_barrier(0); } while (0)
#define PCHK(V,F) F = ((((V)[0]>>16)^tgt)|(((V)[1]>>16)^tgt)| \
                       (((V)[2]>>16)^tgt)|(((V)[3]>>16)^tgt)) & msk

__global__ void __launch_bounds__(1024, 4)
lstm_scan(const float* __restrict__ x,
          const float* __restrict__ Wih,
          const float* __restrict__ Whh,
          const float* __restrict__ bih,
          const float* __restrict__ bhh,
          const float* __restrict__ Wfc,
          const float* __restrict__ bfc,
          float* __restrict__ out,
          unsigned* __restrict__ hq)    // [2][B_TOT][HID] tagged h words
{
    __shared__ __align__(16) char act[2][CHUNK*ROWB];  // double-buffered, swizzled

    const int tid  = threadIdx.x;
    const int w    = tid >> 6;       // wave 0..15
    const int lane = tid & 63;
    const int lr   = lane & 15;
    const int kg   = lane >> 4;
    const int chunk= blockIdx.x & 15;
    const int jw   = blockIdx.x >> 4;    // 0..3
    const int cb   = chunk*CHUNK;

    // wave w owns all 4 gates of j-block [jw*64 + w*4, +4)
    const int q4   = lr >> 2;            // gate index (i,f,g,o) of this col
    const int j4   = lr & 3;             // j within the 4-block
    const int n    = q4*HID + jw*JSL + w*4 + j4;
    const int prow = kg*4 + q4;          // owned batch row (cell phase)
    const int pj   = w*4 + j4;           // owned j-local (cell phase)

    // ---- register-resident weight fragments (B operand), 40 VGPRs ----
    half8 wv[NKK];
    const float bias = bih[n] + bhh[n];
    #pragma unroll
    for (int kk = 0; kk < 2; ++kk)
        #pragma unroll
        for (int jj = 0; jj < 8; ++jj)
            wv[kk][jj] = (_Float16)Wih[n*NIN + kk*32 + kg*8 + jj];
    #pragma unroll
    for (int kk = 2; kk < NKK; ++kk)
        #pragma unroll
        for (int jj = 0; jj < 8; ++jj)
            wv[kk][jj] = (_Float16)Whh[n*HID + kk*32 + kg*8 + jj - NIN];

    // ---- init both act buffers: zeros (h_0 = 0), x_0 into buf 0 ----
    for (int i = tid; i < 2*CHUNK*ROWB/4; i += 1024) ((int*)act)[i] = 0;
    __syncthreads();
    {
        float x0 = x[((size_t)(cb + w)*T_SEQ + 0)*NIN + lane];
        *(unsigned short*)(act[0] + w*ROWB + ((lane*2) ^ (w << 4))) = f2h_bits(x0);
    }
    __syncthreads();

    float cst = 0.f, hlast = 0.f;

    // gather role: wave w polls row w; lane = (partner gp, 16B chunk gq)
    const int gp  = lane >> 4, gq = lane & 15;
    const int gpj = (jw + 1 + gp) & 3;
    const unsigned msk = (gp < 3) ? 0xFFFFFFFFu : 0u;

    for (int t = 0; t < T_SEQ; ++t) {
        const char* acur = act[t & 1];
        char*       anx  = act[(t & 1) ^ 1];

        const int tn = (t+1 < T_SEQ) ? t+1 : T_SEQ-1;
        const float xv = x[((size_t)(cb + w)*T_SEQ + tn)*NIN + lane];

        // A fragments (row lr, swizzled, conflict-free); 2 parallel MFMA chains
        half8 af[NKK];
        #pragma unroll
        for (int kk = 0; kk < NKK; ++kk) {
            const int off = (kk*64 + kg*16) ^ (lr << 4);
            af[kk] = *(const half8*)(acur + lr*ROWB + off);
        }
        f32x4 aa = {bias, bias, bias, bias};
        f32x4 ab = {0.f, 0.f, 0.f, 0.f};
        #pragma unroll
        for (int kk = 0; kk < NKK; kk += 2) {
            aa = __builtin_amdgcn_mfma_f32_16x16x32_f16(af[kk],   wv[kk],   aa, 0, 0, 0);
            ab = __builtin_amdgcn_mfma_f32_16x16x32_f16(af[kk+1], wv[kk+1], ab, 0, 0, 0);
        }
        const f32x4 acc = aa + ab;

        // in-wave transpose: lane (kg,q4,j4) needs acc[q4] of lanes
        // (kg, r*4 + j4), r=0..3. BitMode: and=0x13 keeps {lane&3, lane&16},
        // or = r<<2 selects source column group.
        float gate[4];
        #pragma unroll
        for (int r = 0; r < 4; ++r) {
            const float g0 = swz<0x013>(acc[r]);   // or=0<<2, and=0x13
            const float g1 = swz<0x093>(acc[r]);   // or=1<<2
            const float g2 = swz<0x113>(acc[r]);   // or=2<<2
            const float g3 = swz<0x193>(acc[r]);   // or=3<<2
            if (q4 == r) { gate[0]=g0; gate[1]=g1; gate[2]=g2; gate[3]=g3; }
        }

        // cell update: lane owns (prow, j = jw*64 + pj) -- no barrier needed
        const float iv = sigf(gate[0]);
        const float fv = sigf(gate[1]);
        const float gv = tanhf_fast(gate[2]);
        const float ov = sigf(gate[3]);
        const float cc = fv*cst + iv*gv;
        cst = cc;
        const float hv = ov*tanhf_fast(cc);
        hlast = hv;
        const unsigned short h16 = f2h_bits(hv);

        const unsigned tgt = (unsigned)(t+1);
        unsigned* hqp = hq + (size_t)(tgt & 1u)*B_TOT*HID;

        // publish immediately: paired u64 atomicExch (LLC-resident)
        {
            const unsigned myw = (tgt << 16) | (unsigned)h16;
            const unsigned otw = __shfl_xor(myw, 1);
            if (!(lane & 1)) {
                const unsigned long long pk =
                    ((unsigned long long)otw << 32) | (unsigned long long)myw;
                (void)__hip_atomic_exchange(
                    (unsigned long long*)(hqp + (size_t)(cb+prow)*HID + jw*JSL + pj),
                    pk, __ATOMIC_RELAXED, __HIP_MEMORY_SCOPE_AGENT);
            }
        }

        // own h (paired u32) + x_{t+1} into act_next
        {
            const unsigned hx = __shfl_xor((unsigned)h16, 1);
            if (!(lane & 1)) {
                const int c = NIN + jw*JSL + pj;   // even
                *(unsigned*)(anx + prow*ROWB + ((c*2) ^ (prow << 4))) =
                    (hx << 16) | (unsigned)h16;
            }
            if (t < T_SEQ-1)
                *(unsigned short*)(anx + w*ROWB + ((lane*2) ^ (w << 4))) = f2h_bits(xv);
        }

        // gather partners' h_t: 3-deep pipelined tagged poll (counted vmcnt)
        if (t < T_SEQ-1) {
            const unsigned* ap = hqp + (size_t)(cb+w)*HID + gpj*JSL + gq*4;
            u32x4 va, vb, vc, vg;
            PISSUE(va); PISSUE(vb); PISSUE(vc);
            for (;;) {
                unsigned f;
                PWAIT(); PCHK(va, f);
                if (!__any(f != 0u)) { vg = va; break; }
                PISSUE(va);
                PWAIT(); PCHK(vb, f);
                if (!__any(f != 0u)) { vg = vb; break; }
                PISSUE(vb);
                PWAIT(); PCHK(vc, f);
                if (!__any(f != 0u)) { vg = vc; break; }
                PISSUE(vc);
            }
            asm volatile("s_waitcnt vmcnt(0)" ::: "memory");  // drain in-flight
            if (gp < 3) {
                const int c0 = NIN + gpj*JSL + gq*4;
                const unsigned d0 = (vg[0] & 0xFFFFu) | (vg[1] << 16);
                const unsigned d1 = (vg[2] & 0xFFFFu) | (vg[3] << 16);
                *(unsigned long long*)(anx + w*ROWB + ((c0*2) ^ (w << 4))) =
                    ((unsigned long long)d1 << 32) | (unsigned long long)d0;
            }
        }

        __syncthreads();   // single barrier: act_next complete
    }

    // ---- final FC: lane holds h(prow, jw*64+pj); reduce 4-j groups ----
    {
        float v = Wfc[jw*JSL + pj] * hlast;
        v += __shfl_xor(v, 1);
        v += __shfl_xor(v, 2);
        if (j4 == 0) {
            if (jw == 0 && w == 0) v += bfc[0];
            atomicAdd(&out[cb + prow], v);
        }
    }
}

extern "C" void kernel_launch(void* const* d_in, const int* in_sizes, int n_in,
                              void* d_out, int out_size, void* d_ws, size_t ws_size,
                              hipStream_t stream)
{
    const float* x   = (const float*)d_in[0];
    const float* Wih = (const float*)d_in[1];
    const float* Whh = (const float*)d_in[2];
    const float* bih = (const float*)d_in[3];
    const float* bhh = (const float*)d_in[4];
    const float* Wfc = (const float*)d_in[5];
    const float* bfc = (const float*)d_in[6];
    float* out = (float*)d_out;

    unsigned* hq = (unsigned*)d_ws;   // [2][256][256] tagged words

    hipMemsetAsync(hq, 0, (size_t)2*B_TOT*HID*sizeof(unsigned), stream);
    hipMemsetAsync(d_out, 0, out_size*sizeof(float), stream);
    lstm_scan<<<NWG, 1024, 0, stream>>>(x, Wih, Whh, bih, bhh, Wfc, bfc,
                                        out, hq);
}

// Round 12
// 1212.720 us; speedup vs baseline: 1.1522x; 1.1522x over previous
//
#include <hip/hip_runtime.h>
#include <hip/hip_bf16.h>

// LSTM B=256,T=512,I=64,H=256. 64 WGs x 1024 thr, 4-way j-split (round-8 core).
// Round 12: K-split software pipeline -- remote-k MFMAs finish step t, then
// cell+publish+poll-issue, then LOCAL-k MFMAs of step t+1 run under the LLC
// round-trip. Raw barriers (lgkmcnt only, no vmcnt drain) keep the publish
// ack and polls off the critical path. 3-deep rotating poll, counted vmcnt.

#define B_TOT 256
#define T_SEQ 512
#define NIN   64
#define HID   256
#define CHUNK 16
#define JSL   64            // j per WG (4-way split)
#define ROWB  768           // LDS act row stride bytes (320 f16 = 640B data)
#define NKK   10            // K = 320 = 10*32
#define NWG   64

typedef _Float16 half8 __attribute__((ext_vector_type(8)));
typedef float    f32x4 __attribute__((ext_vector_type(4)));
typedef unsigned u32x4 __attribute__((ext_vector_type(4)));

__device__ __forceinline__ float fast_rcp(float x){ return __builtin_amdgcn_rcpf(x); }
__device__ __forceinline__ float sigf(float v){ return fast_rcp(1.0f+__expf(-v)); }
__device__ __forceinline__ float tanhf_fast(float v){ return 1.0f-2.0f*fast_rcp(__expf(2.0f*v)+1.0f); }
__device__ __forceinline__ unsigned short f2h_bits(float f){
    _Float16 h=(_Float16)f; return __builtin_bit_cast(unsigned short,h);
}

// raw barrier: LDS ordering only -- no vmcnt(0) drain (polls/exch stay in flight)
#define BARRIER() do { asm volatile("s_waitcnt lgkmcnt(0)" ::: "memory"); \
                       __builtin_amdgcn_s_barrier(); \
                       __builtin_amdgcn_sched_barrier(0); } while (0)

#define PISSUE(V) asm volatile("global_load_dwordx4 %0, %1, off sc0 sc1" \
                               : "=v"(V) : "v"(ap) : "memory")
#define PWAIT()   do { asm volatile("s_waitcnt vmcnt(2)" ::: "memory"); \
                       __builtin_amdgcn_sched_barrier(0); } while (0)
#define PCHK(V,F) F = ((((V)[0]>>16)^tgt)|(((V)[1]>>16)^tgt)| \
                       (((V)[2]>>16)^tgt)|(((V)[3]>>16)^tgt)) & msk

__global__ void __launch_bounds__(1024, 4)
lstm_scan(const float* __restrict__ x,
          const float* __restrict__ Wih,
          const float* __restrict__ Whh,
          const float* __restrict__ bih,
          const float* __restrict__ bhh,
          const float* __restrict__ Wfc,
          const float* __restrict__ bfc,
          float* __restrict__ out,
          unsigned* __restrict__ hq)    // [2][B_TOT][HID] tagged h words
{
    __shared__ __align__(16) char act[2][CHUNK*ROWB];  // dbuf, swizzled
    __shared__ float gl[CHUNK][4*JSL + 1];             // [16][257] gate pre-acts

    const int tid  = threadIdx.x;
    const int w    = tid >> 6;       // wave 0..15 (= batch row in cell phase)
    const int lane = tid & 63;
    const int lr   = lane & 15;
    const int kg   = lane >> 4;
    const int chunk= blockIdx.x & 15;
    const int jw   = blockIdx.x >> 4;    // 0..3
    const int cb   = chunk*CHUNK;

    // this wave's 16 gate rows: n = gg*256 + jw*64 + (w&3)*16 + lr
    const int gg = w >> 2;
    const int n  = gg*HID + jw*JSL + (w & 3)*16 + lr;

    // K-order map: kmap[0..3] = local (x, own-h), kmap[4..9] = remote slices
    int kmap[NKK];
    kmap[0] = 0; kmap[1] = 1; kmap[2] = 2 + 2*jw; kmap[3] = 3 + 2*jw;
    {
        int p = 4;
        #pragma unroll
        for (int ko = 0; ko < 4; ++ko)
            if (ko != jw) { kmap[p] = 2 + 2*ko; kmap[p+1] = 3 + 2*ko; p += 2; }
    }

    // ---- register-resident weight fragments in kmap order, 40 VGPRs ----
    half8 wv[NKK];
    const float bias = bih[n] + bhh[n];
    #pragma unroll
    for (int i = 0; i < 2; ++i)            // kmap[0..1] = {0,1}: W_ih
        #pragma unroll
        for (int jj = 0; jj < 8; ++jj)
            wv[i][jj] = (_Float16)Wih[n*NIN + i*32 + kg*8 + jj];
    #pragma unroll
    for (int i = 2; i < NKK; ++i)          // kmap[2..9] >= 2: W_hh
        #pragma unroll
        for (int jj = 0; jj < 8; ++jj)
            wv[i][jj] = (_Float16)Whh[n*HID + kmap[i]*32 + kg*8 + jj - NIN];

    // ---- init act[0]: zeros (h_0 = 0) then x_0 ----
    for (int i = tid; i < CHUNK*ROWB/4; i += 1024) ((int*)act[0])[i] = 0;
    __syncthreads();
    {
        float x0 = x[(size_t)(cb + w)*T_SEQ*NIN + lane];
        *(unsigned short*)(act[0] + w*ROWB + ((lane*2) ^ (w << 4))) = f2h_bits(x0);
    }
    float xv = x[((size_t)(cb + w)*T_SEQ + 1)*NIN + lane];   // x(1)
    __syncthreads();

    // ---- prologue: local MFMAs for step 0 ----
    f32x4 acc_p = {bias, bias, bias, bias};
    #pragma unroll
    for (int i = 0; i < 4; ++i) {
        const int off = (kmap[i]*64 + kg*16) ^ (lr << 4);
        half8 a = *(const half8*)(act[0] + lr*ROWB + off);
        acc_p = __builtin_amdgcn_mfma_f32_16x16x32_f16(a, wv[i], acc_p, 0, 0, 0);
    }

    float cst = 0.f, hlast = 0.f;

    const int gp  = lane >> 4, gq = lane & 15;   // poll role
    const int gpj = (jw + 1 + gp) & 3;
    const unsigned msk = (gp < 3) ? 0xFFFFFFFFu : 0u;

    for (int t = 0; t < T_SEQ; ++t) {
        const char* acur = act[t & 1];
        char*       anx  = act[(t & 1) ^ 1];

        // Phase 1: finish gates(t) -- 6 remote MFMAs (2 parallel chains)
        f32x4 aca = acc_p;
        f32x4 acb = {0.f, 0.f, 0.f, 0.f};
        #pragma unroll
        for (int i = 4; i < NKK; i += 2) {
            const int offa = (kmap[i]*64   + kg*16) ^ (lr << 4);
            const int offb = (kmap[i+1]*64 + kg*16) ^ (lr << 4);
            half8 a0 = *(const half8*)(acur + lr*ROWB + offa);
            half8 a1 = *(const half8*)(acur + lr*ROWB + offb);
            aca = __builtin_amdgcn_mfma_f32_16x16x32_f16(a0, wv[i],   aca, 0, 0, 0);
            acb = __builtin_amdgcn_mfma_f32_16x16x32_f16(a1, wv[i+1], acb, 0, 0, 0);
        }
        const f32x4 acc = aca + acb;

        // gl scatter + B1 + cell
        #pragma unroll
        for (int r = 0; r < 4; ++r)
            gl[kg*4 + r][w*16 + lr] = acc[r];
        BARRIER();   // B1

        const float iv = sigf(gl[w][          lane]);
        const float fv = sigf(gl[w][  JSL  + lane]);
        const float gv = tanhf_fast(gl[w][2*JSL + lane]);
        const float ov = sigf(gl[w][3*JSL + lane]);
        const float cc = fv*cst + iv*gv;
        cst = cc;
        const float hv = ov*tanhf_fast(cc);
        hlast = hv;
        const unsigned short h16 = f2h_bits(hv);

        const unsigned tgt = (unsigned)(t+1);
        unsigned* hqp = hq + (size_t)(tgt & 1u)*B_TOT*HID;

        // publish: coalesced per-lane u32 atomicExch (RMW executes at LLC)
        (void)__hip_atomic_exchange(hqp + (size_t)(cb + w)*HID + jw*JSL + lane,
                                    (tgt << 16) | (unsigned)h16,
                                    __ATOMIC_RELAXED, __HIP_MEMORY_SCOPE_AGENT);

        // own h(t+1) + x(t+1) into act_next
        {
            const int c = NIN + jw*JSL + lane;
            *(unsigned short*)(anx + w*ROWB + ((c*2) ^ (w << 4))) = h16;
            *(unsigned short*)(anx + w*ROWB + ((lane*2) ^ (w << 4))) = f2h_bits(xv);
        }

        // Phase 3: issue polls for partner h(t+1), then x(t+3) reg prefetch
        const bool dopoll = (t < T_SEQ-1);
        u32x4 va, vb, vc, vg;
        const unsigned* ap = hqp + (size_t)(cb + w)*HID + gpj*JSL + gq*4;
        if (dopoll) { PISSUE(va); PISSUE(vb); PISSUE(vc); }
        {
            const int tn = (t+2 < T_SEQ) ? t+2 : T_SEQ-1;
            xv = x[((size_t)(cb + w)*T_SEQ + tn)*NIN + lane];
        }

        BARRIER();   // B2: anx local cols (x, own-h) visible

        // Phase 4 (overlap window): local MFMAs of step t+1
        acc_p = (f32x4){bias, bias, bias, bias};
        #pragma unroll
        for (int i = 0; i < 4; ++i) {
            const int off = (kmap[i]*64 + kg*16) ^ (lr << 4);
            half8 a = *(const half8*)(anx + lr*ROWB + off);
            acc_p = __builtin_amdgcn_mfma_f32_16x16x32_f16(a, wv[i], acc_p, 0, 0, 0);
        }

        // Phase 5: poll detect (3-deep rotating, counted vmcnt) + partner write
        if (dopoll) {
            for (;;) {
                unsigned f;
                PWAIT(); PCHK(va, f);
                if (!__any(f != 0u)) { vg = va; break; }
                PISSUE(va);
                PWAIT(); PCHK(vb, f);
                if (!__any(f != 0u)) { vg = vb; break; }
                PISSUE(vb);
                PWAIT(); PCHK(vc, f);
                if (!__any(f != 0u)) { vg = vc; break; }
                PISSUE(vc);
            }
            asm volatile("s_waitcnt vmcnt(0)" ::: "memory");  // drain in-flight
            if (gp < 3) {
                const int c0 = NIN + gpj*JSL + gq*4;
                const unsigned d0 = (vg[0] & 0xFFFFu) | (vg[1] << 16);
                const unsigned d1 = (vg[2] & 0xFFFFu) | (vg[3] << 16);
                *(unsigned long long*)(anx + w*ROWB + ((c0*2) ^ (w << 4))) =
                    ((unsigned long long)d1 << 32) | (unsigned long long)d0;
            }
        }

        BARRIER();   // B3: partner cols visible for next phase 1
    }

    // ---- final FC: partial dot over this WG's 64 j, atomicAdd into out ----
    {
        float v = Wfc[jw*JSL + lane] * hlast;
        if (jw == 0 && lane == 0) v += bfc[0];
        #pragma unroll
        for (int off = 32; off; off >>= 1) v += __shfl_down(v, off);
        if (lane == 0) atomicAdd(&out[cb + w], v);
    }
}

extern "C" void kernel_launch(void* const* d_in, const int* in_sizes, int n_in,
                              void* d_out, int out_size, void* d_ws, size_t ws_size,
                              hipStream_t stream)
{
    const float* x   = (const float*)d_in[0];
    const float* Wih = (const float*)d_in[1];
    const float* Whh = (const float*)d_in[2];
    const float* bih = (const float*)d_in[3];
    const float* bhh = (const float*)d_in[4];
    const float* Wfc = (const float*)d_in[5];
    const float* bfc = (const float*)d_in[6];
    float* out = (float*)d_out;

    unsigned* hq = (unsigned*)d_ws;   // [2][256][256] tagged words

    hipMemsetAsync(hq, 0, (size_t)2*B_TOT*HID*sizeof(unsigned), stream);
    hipMemsetAsync(d_out, 0, out_size*sizeof(float), stream);
    lstm_scan<<<NWG, 1024, 0, stream>>>(x, Wih, Whh, bih, bhh, Wfc, bfc,
                                        out, hq);
}

// Round 13
// 885.330 us; speedup vs baseline: 1.5783x; 1.3698x over previous
//
#include <hip/hip_runtime.h>
#include <hip/hip_bf16.h>

// LSTM B=256,T=512,I=64,H=256. 64 WGs x 1024 thr, 4-way j-split (round-8 core).
// Round 13: single change vs round 8 -- the poll. 3-deep rotating sc0 sc1
// dwordx4 probes with uniform hand-counted vmcnt(2) (queue [exch,va,vb,vc]),
// so probes stay in flight and detect costs ~RT instead of ~2xRT. No drain on
// exit: va/vb/vc live ranges extended past B2's natural vmcnt(0) via dummy use.

#define B_TOT 256
#define T_SEQ 512
#define NIN   64
#define HID   256
#define CHUNK 16
#define JSL   64            // j per WG (4-way split)
#define ROWB  768           // LDS act row stride bytes (320 f16 = 640B data)
#define NKK   10            // K = 320 = 10*32
#define NWG   64

typedef _Float16 half8 __attribute__((ext_vector_type(8)));
typedef float    f32x4 __attribute__((ext_vector_type(4)));
typedef unsigned u32x4 __attribute__((ext_vector_type(4)));

__device__ __forceinline__ float fast_rcp(float x){ return __builtin_amdgcn_rcpf(x); }
__device__ __forceinline__ float sigf(float v){ return fast_rcp(1.0f+__expf(-v)); }
__device__ __forceinline__ float tanhf_fast(float v){ return 1.0f-2.0f*fast_rcp(__expf(2.0f*v)+1.0f); }
__device__ __forceinline__ unsigned short f2h_bits(float f){
    _Float16 h=(_Float16)f; return __builtin_bit_cast(unsigned short,h);
}

#define PISSUE(V) asm volatile("global_load_dwordx4 %0, %1, off sc0 sc1" \
                               : "=v"(V) : "v"(ap) : "memory")
#define PW2()     do { asm volatile("s_waitcnt vmcnt(2)" ::: "memory"); \
                       __builtin_amdgcn_sched_barrier(0); } while (0)
#define PCHK(V,F) F = ((((V)[0]>>16)^tgt)|(((V)[1]>>16)^tgt)| \
                       (((V)[2]>>16)^tgt)|(((V)[3]>>16)^tgt)) & msk

__global__ void __launch_bounds__(1024, 4)
lstm_scan(const float* __restrict__ x,
          const float* __restrict__ Wih,
          const float* __restrict__ Whh,
          const float* __restrict__ bih,
          const float* __restrict__ bhh,
          const float* __restrict__ Wfc,
          const float* __restrict__ bfc,
          float* __restrict__ out,
          unsigned* __restrict__ hq)    // [2][B_TOT][HID] tagged h words
{
    __shared__ __align__(16) char act[CHUNK*ROWB];   // [16 rows][320 f16] swizzled
    __shared__ float gl[CHUNK][4*JSL + 1];           // [16][257] gate pre-acts

    const int tid  = threadIdx.x;
    const int w    = tid >> 6;       // wave 0..15 (= batch row in cell phase)
    const int lane = tid & 63;
    const int lr   = lane & 15;
    const int kg   = lane >> 4;
    const int chunk= blockIdx.x & 15;
    const int jw   = blockIdx.x >> 4;    // 0..3
    const int cb   = chunk*CHUNK;

    // this wave's 16 gate rows: n = gg*256 + jw*64 + (w&3)*16 + lr
    const int gg = w >> 2;
    const int n  = gg*HID + jw*JSL + (w & 3)*16 + lr;

    // ---- register-resident weight fragments (B operand), 40 VGPRs ----
    half8 wv[NKK];
    const float bias = bih[n] + bhh[n];
    #pragma unroll
    for (int kk = 0; kk < 2; ++kk)
        #pragma unroll
        for (int jj = 0; jj < 8; ++jj)
            wv[kk][jj] = (_Float16)Wih[n*NIN + kk*32 + kg*8 + jj];
    #pragma unroll
    for (int kk = 2; kk < NKK; ++kk)
        #pragma unroll
        for (int jj = 0; jj < 8; ++jj)
            wv[kk][jj] = (_Float16)Whh[n*HID + kk*32 + kg*8 + jj - NIN];

    // ---- init act: zeros (h_0 = 0) then x_0 ----
    for (int i = tid; i < CHUNK*ROWB/4; i += 1024) ((int*)act)[i] = 0;
    __syncthreads();
    {
        float x0 = x[((size_t)(cb + w)*T_SEQ + 0)*NIN + lane];
        *(unsigned short*)(act + w*ROWB + ((lane*2) ^ (w << 4))) = f2h_bits(x0);
    }
    __syncthreads();

    float cst = 0.f, hlast = 0.f;

    // gather role for this lane: partner gp (0..2; 3 = idle), 16B chunk gq
    const int gp   = lane >> 4;
    const int gq   = lane & 15;
    const int gpj  = (jw + 1 + gp) & 3;
    const unsigned msk = (gp < 3) ? 0xFFFFFFFFu : 0u;

    for (int t = 0; t < T_SEQ; ++t) {
        // prefetch x_{t+1}; completes (and is consumed) before any poll asm
        const int tn = (t+1 < T_SEQ) ? t+1 : T_SEQ-1;
        const float xv = x[((size_t)(cb + w)*T_SEQ + tn)*NIN + lane];

        // A fragments from act (row lr, swizzled, conflict-free)
        half8 af[NKK];
        #pragma unroll
        for (int kk = 0; kk < NKK; ++kk) {
            const int off = (kk*64 + kg*16) ^ (lr << 4);
            af[kk] = *(const half8*)(act + lr*ROWB + off);
        }
        f32x4 aca = {bias, bias, bias, bias};
        f32x4 acb = {0.f, 0.f, 0.f, 0.f};
        #pragma unroll
        for (int kk = 0; kk < NKK; kk += 2) {
            aca = __builtin_amdgcn_mfma_f32_16x16x32_f16(af[kk],   wv[kk],   aca, 0, 0, 0);
            acb = __builtin_amdgcn_mfma_f32_16x16x32_f16(af[kk+1], wv[kk+1], acb, 0, 0, 0);
        }
        const f32x4 acc = aca + acb;

        // scatter pre-activations: (row kg*4+r, col w*16+lr)
        #pragma unroll
        for (int r = 0; r < 4; ++r)
            gl[kg*4 + r][w*16 + lr] = acc[r];
        __syncthreads();   // B1: gl ready; af reads done -> act writable

        // cell update: thread owns (row=w, jloc=lane)
        const float iv = sigf(gl[w][          lane]);
        const float fv = sigf(gl[w][  JSL  + lane]);
        const float gv = tanhf_fast(gl[w][2*JSL + lane]);
        const float ov = sigf(gl[w][3*JSL + lane]);
        const float cc = fv*cst + iv*gv;
        cst = cc;
        const float hv = ov*tanhf_fast(cc);
        hlast = hv;
        const unsigned short h16 = f2h_bits(hv);

        const unsigned tgt = (unsigned)(t+1);
        unsigned* hb = hq + ((size_t)(tgt & 1u)*B_TOT + (cb + w))*HID;

        // publish: coalesced per-lane u32 atomicExch (RMW executes at the LLC,
        // line stays resident) -- first VMEM in the hand-counted queue
        (void)__hip_atomic_exchange(hb + jw*JSL + lane,
                                    (tgt << 16) | (unsigned)h16,
                                    __ATOMIC_RELAXED, __HIP_MEMORY_SCOPE_AGENT);

        // own h + x_{t+1} into act (LDS only; lgkmcnt, not vmcnt)
        {
            const int c = NIN + jw*JSL + lane;
            *(unsigned short*)(act + w*ROWB + ((c*2) ^ (w << 4))) = h16;
            if (t < T_SEQ-1)
                *(unsigned short*)(act + w*ROWB + ((lane*2) ^ (w << 4))) = f2h_bits(xv);
        }

        // 3-deep rotating poll. Queue: [exch, va, vb, vc]; every vmcnt(2)
        // retires exactly the oldest probe (first also retires the exch ack).
        u32x4 va, vb, vc, vg;
        {
            const unsigned* ap = hb + (gpj*JSL + gq*4);
            PISSUE(va); PISSUE(vb); PISSUE(vc);
            for (;;) {
                unsigned f;
                PW2(); PCHK(va, f);
                if (!__any(f != 0u)) { vg = va; break; }
                PISSUE(va);
                PW2(); PCHK(vb, f);
                if (!__any(f != 0u)) { vg = vb; break; }
                PISSUE(vb);
                PW2(); PCHK(vc, f);
                if (!__any(f != 0u)) { vg = vc; break; }
                PISSUE(vc);
            }
        }
        // partner h into act (no vmcnt(0) drain here -- B2 drains naturally)
        if (gp < 3) {
            const int c0 = NIN + gpj*JSL + gq*4;
            const unsigned d0 = (vg[0] & 0xFFFFu) | (vg[1] << 16);
            const unsigned d1 = (vg[2] & 0xFFFFu) | (vg[3] << 16);
            *(unsigned long long*)(act + w*ROWB + ((c0*2) ^ (w << 4))) =
                ((unsigned long long)d1 << 32) | (unsigned long long)d0;
        }

        __syncthreads();   // B2: act ready; implicit vmcnt(0) drains leftovers

        // keep-alive: in-flight reissued probes target va/vb/vc registers;
        // extending their live range past B2's drain prevents register reuse
        // while loads are still landing.
        asm volatile("" :: "v"(va), "v"(vb), "v"(vc));
    }

    // ---- final FC: partial dot over this WG's 64 j, atomicAdd into out ----
    {
        float v = Wfc[jw*JSL + lane] * hlast;
        if (jw == 0 && lane == 0) v += bfc[0];
        #pragma unroll
        for (int off = 32; off; off >>= 1) v += __shfl_down(v, off);
        if (lane == 0) atomicAdd(&out[cb + w], v);
    }
}

extern "C" void kernel_launch(void* const* d_in, const int* in_sizes, int n_in,
                              void* d_out, int out_size, void* d_ws, size_t ws_size,
                              hipStream_t stream)
{
    const float* x   = (const float*)d_in[0];
    const float* Wih = (const float*)d_in[1];
    const float* Whh = (const float*)d_in[2];
    const float* bih = (const float*)d_in[3];
    const float* bhh = (const float*)d_in[4];
    const float* Wfc = (const float*)d_in[5];
    const float* bfc = (const float*)d_in[6];
    float* out = (float*)d_out;

    unsigned* hq = (unsigned*)d_ws;   // [2][256][256] tagged words

    hipMemsetAsync(hq, 0, (size_t)2*B_TOT*HID*sizeof(unsigned), stream);
    hipMemsetAsync(d_out, 0, out_size*sizeof(float), stream);
    lstm_scan<<<NWG, 1024, 0, stream>>>(x, Wih, Whh, bih, bhh, Wfc, bfc,
                                        out, hq);
}